// Round 12
// baseline (666.579 us; speedup 1.0000x reference)
//
#include <hip/hip_runtime.h>

#define RELUF 1
#define ACCF  2
#define PCH   16
#define NWT   19
#define SCH   2048

typedef unsigned short ushort_t;
typedef __attribute__((ext_vector_type(8))) short bf16x8;
typedef __attribute__((ext_vector_type(4))) float f32x4;

__device__ __forceinline__ float bf2f(unsigned int v) {
    return __uint_as_float(v << 16);
}
__device__ __forceinline__ unsigned int f2bu(float f) {
    unsigned int u = __float_as_uint(f);
    return (u + 0x7fffu + ((u >> 16) & 1u)) >> 16;
}

// ---------------- utility ----------------
__global__ void zero_i32_kernel(int* __restrict__ p, int n) {
    int i = blockIdx.x * blockDim.x + threadIdx.x;
    if (i < n) p[i] = 0;
}
__global__ void seg_bounds_kernel(const int* __restrict__ batch, int* __restrict__ bstart,
                                  int* __restrict__ bend, int N) {
    int n = blockIdx.x * blockDim.x + threadIdx.x;
    if (n >= N) return;
    int b = batch[n];
    if (n == 0) bstart[b] = 0;
    else {
        int pb = batch[n - 1];
        if (pb != b) { bstart[b] = n; bend[pb] = n; }
    }
    if (n == N - 1) bend[b] = N;
}

// ---------- parallel 3-phase scan (+ dinv fused into phase 3) ----------
__global__ void scan1_kernel(const int* __restrict__ degi, int* __restrict__ rowptr,
                             int* __restrict__ bsum, int n) {
    __shared__ int sh[256];
    int tid = threadIdx.x;
    int base = blockIdx.x * SCH + tid * 8;
    int loc[8]; int s = 0;
#pragma unroll
    for (int j = 0; j < 8; j++) {
        int idx = base + j;
        int v = (idx < n) ? degi[idx] : 0;
        s += v; loc[j] = s;
    }
    sh[tid] = s;
    __syncthreads();
    for (int off = 1; off < 256; off <<= 1) {
        int t = (tid >= off) ? sh[tid - off] : 0;
        __syncthreads();
        sh[tid] += t;
        __syncthreads();
    }
    int prev = (tid > 0) ? sh[tid - 1] : 0;
#pragma unroll
    for (int j = 0; j < 8; j++) {
        int idx = base + j;
        if (idx < n) rowptr[idx + 1] = prev + loc[j];
    }
    if (tid == 255) bsum[blockIdx.x] = sh[255];
}
__global__ void scan2_kernel(int* __restrict__ bsum, int nb) {
    __shared__ int sh[256];
    int tid = threadIdx.x;
    sh[tid] = (tid < nb) ? bsum[tid] : 0;
    __syncthreads();
    for (int off = 1; off < 256; off <<= 1) {
        int t = (tid >= off) ? sh[tid - off] : 0;
        __syncthreads();
        sh[tid] += t;
        __syncthreads();
    }
    if (tid < nb) bsum[tid] = (tid > 0) ? sh[tid - 1] : 0;
}
__global__ void scan3_kernel(int* __restrict__ rowptr, const int* __restrict__ bsum,
                             const int* __restrict__ degi,
                             float* __restrict__ dinv, float* __restrict__ dinvl, int n) {
    int i = blockIdx.x * blockDim.x + threadIdx.x;
    if (i == 0) rowptr[0] = 0;
    if (i < n) {
        rowptr[i + 1] += bsum[i / SCH];
        float deg = (float)degi[i];
        dinv[i] = (deg > 0.f) ? rsqrtf(fmaxf(deg, 1.f)) : 0.f;
        dinvl[i] = rsqrtf(deg + 1.f);
    }
}

// ---------- batched W transpose+convert ----------
struct WtPack {
    const float* src[NWT];
    unsigned long long off[NWT];
    int K[NWT];
};
__global__ void wconv_kernel(WtPack p, ushort_t* __restrict__ base) {
    int a = blockIdx.y;
    const float* s = p.src[a];
    ushort_t* d = base + p.off[a];
    int K = p.K[a];
    int total = K * 128;
    for (int i = blockIdx.x * blockDim.x + threadIdx.x; i < total; i += gridDim.x * blockDim.x) {
        int k = i >> 7, n = i & 127;
        d[n * K + k] = (ushort_t)f2bu(s[i]);
    }
}

// ---------- fp32-A MFMA GEMM (hr path): C fp32 ----------
__global__ __launch_bounds__(256)
void gemm_f32_kernel(const float* __restrict__ A, int lda,
                     const ushort_t* __restrict__ Wt,
                     float* __restrict__ C, int ldc,
                     int M, int K,
                     const float* __restrict__ bias)
{
    __shared__ ushort_t As[64][40];
    __shared__ ushort_t Bs[128][40];
    const int tid = threadIdx.x;
    const int m0 = blockIdx.x * 64;
    const int lane = tid & 63;
    const int wv = tid >> 6;
    const int q = lane >> 4;
    const int l16 = lane & 15;
    const int sar = tid >> 2;
    const int sak = (tid & 3) << 3;
    const int sbn = tid >> 1;
    const int sbk = (tid & 1) << 4;
    const bool arow_ok = (m0 + sar) < M;
    const float* Arow = A + (size_t)(m0 + sar) * lda;
    const ushort_t* Wrow = Wt + (size_t)sbn * K;

    f32x4 acc[8];
#pragma unroll
    for (int t = 0; t < 8; t++) acc[t] = (f32x4){0.f, 0.f, 0.f, 0.f};

    for (int k0 = 0; k0 < K; k0 += 32) {
        uint4 apk;
        if (arow_ok && k0 + sak + 8 <= K) {
            float4 p0 = *(const float4*)(Arow + k0 + sak);
            float4 p1 = *(const float4*)(Arow + k0 + sak + 4);
            apk.x = f2bu(p0.x) | (f2bu(p0.y) << 16);
            apk.y = f2bu(p0.z) | (f2bu(p0.w) << 16);
            apk.z = f2bu(p1.x) | (f2bu(p1.y) << 16);
            apk.w = f2bu(p1.z) | (f2bu(p1.w) << 16);
        } else {
            unsigned int t4[4] = {0, 0, 0, 0};
            for (int j = 0; j < 8; j++) {
                int k = k0 + sak + j;
                unsigned int bv = (arow_ok && k < K) ? f2bu(Arow[k]) : 0u;
                t4[j >> 1] |= bv << ((j & 1) * 16);
            }
            apk = make_uint4(t4[0], t4[1], t4[2], t4[3]);
        }
        uint4 b0, b1;
        if (k0 + sbk + 16 <= K) {
            b0 = *(const uint4*)(Wrow + k0 + sbk);
            b1 = *(const uint4*)(Wrow + k0 + sbk + 8);
        } else {
            unsigned int t8[8] = {0, 0, 0, 0, 0, 0, 0, 0};
            for (int j = 0; j < 16; j++) {
                int k = k0 + sbk + j;
                unsigned int bv = (k < K) ? (unsigned int)Wrow[k] : 0u;
                t8[j >> 1] |= bv << ((j & 1) * 16);
            }
            b0 = make_uint4(t8[0], t8[1], t8[2], t8[3]);
            b1 = make_uint4(t8[4], t8[5], t8[6], t8[7]);
        }
        __syncthreads();
        *(uint4*)&As[sar][sak] = apk;
        *(uint4*)&Bs[sbn][sbk] = b0;
        *(uint4*)&Bs[sbn][sbk + 8] = b1;
        __syncthreads();
        bf16x8 af = *(const bf16x8*)&As[16 * wv + l16][q * 8];
#pragma unroll
        for (int t = 0; t < 8; t++) {
            bf16x8 bf = *(const bf16x8*)&Bs[t * 16 + l16][q * 8];
            acc[t] = __builtin_amdgcn_mfma_f32_16x16x32_bf16(af, bf, acc[t], 0, 0, 0);
        }
    }
#pragma unroll
    for (int t = 0; t < 8; t++) {
        int col = t * 16 + l16;
        float bb = bias ? bias[col] : 0.f;
#pragma unroll
        for (int r = 0; r < 4; r++) {
            int row = m0 + 16 * wv + q * 4 + r;
            if (row < M) C[(size_t)row * ldc + col] = acc[t][r] + bb;
        }
    }
}

// ---------- bf16-A MFMA GEMM: Cb bf16 in/out, K=128 ----------
__global__ __launch_bounds__(256)
void gemm_bf_kernel(const ushort_t* __restrict__ A,
                    const ushort_t* __restrict__ Wt,
                    ushort_t* __restrict__ Cb,
                    int M, const float* __restrict__ bias, int flags)
{
    const int K = 128;
    __shared__ ushort_t As[64][40];
    __shared__ ushort_t Bs[128][40];
    const int tid = threadIdx.x;
    const int m0 = blockIdx.x * 64;
    const int lane = tid & 63;
    const int wv = tid >> 6;
    const int q = lane >> 4;
    const int l16 = lane & 15;
    const int sar = tid >> 2;
    const int sak = (tid & 3) << 3;
    const int sbn = tid >> 1;
    const int sbk = (tid & 1) << 4;
    const bool arow_ok = (m0 + sar) < M;
    const ushort_t* Arow = A + (size_t)(m0 + sar) * K;
    const ushort_t* Wrow = Wt + (size_t)sbn * K;

    f32x4 acc[8];
#pragma unroll
    for (int t = 0; t < 8; t++) acc[t] = (f32x4){0.f, 0.f, 0.f, 0.f};

    for (int k0 = 0; k0 < K; k0 += 32) {
        uint4 apk = arow_ok ? *(const uint4*)(Arow + k0 + sak) : make_uint4(0, 0, 0, 0);
        uint4 b0 = *(const uint4*)(Wrow + k0 + sbk);
        uint4 b1 = *(const uint4*)(Wrow + k0 + sbk + 8);
        __syncthreads();
        *(uint4*)&As[sar][sak] = apk;
        *(uint4*)&Bs[sbn][sbk] = b0;
        *(uint4*)&Bs[sbn][sbk + 8] = b1;
        __syncthreads();
        bf16x8 af = *(const bf16x8*)&As[16 * wv + l16][q * 8];
#pragma unroll
        for (int t = 0; t < 8; t++) {
            bf16x8 bf = *(const bf16x8*)&Bs[t * 16 + l16][q * 8];
            acc[t] = __builtin_amdgcn_mfma_f32_16x16x32_bf16(af, bf, acc[t], 0, 0, 0);
        }
    }
#pragma unroll
    for (int t = 0; t < 8; t++) {
        int col = t * 16 + l16;
        float bb = bias ? bias[col] : 0.f;
#pragma unroll
        for (int r = 0; r < 4; r++) {
            int row = m0 + 16 * wv + q * 4 + r;
            bool ok = row < M;
            float val = acc[t][r] + bb;
            if ((flags & ACCF) && ok) val += bf2f(Cb[(size_t)row * 128 + col]);
            if (flags & RELUF) val = fmaxf(val, 0.f);
            float other = __shfl_xor(val, 1);
            if (!(lane & 1) && ok) {
                unsigned int pk = f2bu(val) | (f2bu(other) << 16);
                *(unsigned int*)(Cb + (size_t)row * 128 + col) = pk;
            }
        }
    }
}

// ---------- bf16 dual GEMM: Cb = A1@W1 + A2@W2 (+bias)(+relu) ----------
__global__ __launch_bounds__(256)
void gemm_dual_kernel(const ushort_t* __restrict__ A1, const ushort_t* __restrict__ Wt1,
                      const ushort_t* __restrict__ A2, const ushort_t* __restrict__ Wt2,
                      ushort_t* __restrict__ Cb, int M,
                      const float* __restrict__ bias, int flags)
{
    const int K = 128;
    __shared__ ushort_t As[64][40];
    __shared__ ushort_t Bs[128][40];
    const int tid = threadIdx.x;
    const int m0 = blockIdx.x * 64;
    const int lane = tid & 63;
    const int wv = tid >> 6;
    const int q = lane >> 4;
    const int l16 = lane & 15;
    const int sar = tid >> 2;
    const int sak = (tid & 3) << 3;
    const int sbn = tid >> 1;
    const int sbk = (tid & 1) << 4;
    const bool arow_ok = (m0 + sar) < M;

    f32x4 acc[8];
#pragma unroll
    for (int t = 0; t < 8; t++) acc[t] = (f32x4){0.f, 0.f, 0.f, 0.f};

    for (int ph = 0; ph < 2; ph++) {
        const ushort_t* Arow = (ph ? A2 : A1) + (size_t)(m0 + sar) * K;
        const ushort_t* Wrow = (ph ? Wt2 : Wt1) + (size_t)sbn * K;
        for (int k0 = 0; k0 < K; k0 += 32) {
            uint4 apk = arow_ok ? *(const uint4*)(Arow + k0 + sak) : make_uint4(0, 0, 0, 0);
            uint4 b0 = *(const uint4*)(Wrow + k0 + sbk);
            uint4 b1 = *(const uint4*)(Wrow + k0 + sbk + 8);
            __syncthreads();
            *(uint4*)&As[sar][sak] = apk;
            *(uint4*)&Bs[sbn][sbk] = b0;
            *(uint4*)&Bs[sbn][sbk + 8] = b1;
            __syncthreads();
            bf16x8 af = *(const bf16x8*)&As[16 * wv + l16][q * 8];
#pragma unroll
            for (int t = 0; t < 8; t++) {
                bf16x8 bf = *(const bf16x8*)&Bs[t * 16 + l16][q * 8];
                acc[t] = __builtin_amdgcn_mfma_f32_16x16x32_bf16(af, bf, acc[t], 0, 0, 0);
            }
        }
    }
#pragma unroll
    for (int t = 0; t < 8; t++) {
        int col = t * 16 + l16;
        float bb = bias ? bias[col] : 0.f;
#pragma unroll
        for (int r = 0; r < 4; r++) {
            int row = m0 + 16 * wv + q * 4 + r;
            bool ok = row < M;
            float val = acc[t][r] + bb;
            if (flags & RELUF) val = fmaxf(val, 0.f);
            float other = __shfl_xor(val, 1);
            if (!(lane & 1) && ok) {
                unsigned int pk = f2bu(val) | (f2bu(other) << 16);
                *(unsigned int*)(Cb + (size_t)row * 128 + col) = pk;
            }
        }
    }
}

// ---------- bf16 triple GEMM (QKV) ----------
__global__ __launch_bounds__(256)
void gemm3_kernel(const ushort_t* __restrict__ A,
                  const ushort_t* __restrict__ Wt,
                  ushort_t* __restrict__ qb,
                  int M,
                  const float* __restrict__ b0, const float* __restrict__ b1,
                  const float* __restrict__ b2,
                  ushort_t* __restrict__ kv)
{
    const int K = 128;
    __shared__ ushort_t As[64][40];
    __shared__ ushort_t Bs[384][40];
    const int tid = threadIdx.x;
    const int m0 = blockIdx.x * 64;
    const int lane = tid & 63;
    const int wv = tid >> 6;
    const int q = lane >> 4;
    const int l16 = lane & 15;
    const int sar = tid >> 2;
    const int sak = (tid & 3) << 3;
    const bool arow_ok = (m0 + sar) < M;
    const ushort_t* Arow = A + (size_t)(m0 + sar) * K;

    f32x4 acc[24];
#pragma unroll
    for (int t = 0; t < 24; t++) acc[t] = (f32x4){0.f, 0.f, 0.f, 0.f};

    for (int k0 = 0; k0 < K; k0 += 32) {
        uint4 apk = arow_ok ? *(const uint4*)(Arow + k0 + sak) : make_uint4(0, 0, 0, 0);
        uint4 bv[3][2];
        int rows[3], kofs[3];
#pragma unroll
        for (int j = 0; j < 3; j++) {
            int slot = tid + j * 256;
            rows[j] = slot >> 1;
            kofs[j] = (slot & 1) << 4;
            const ushort_t* Wrow = Wt + (size_t)rows[j] * K + k0 + kofs[j];
            bv[j][0] = *(const uint4*)Wrow;
            bv[j][1] = *(const uint4*)(Wrow + 8);
        }
        __syncthreads();
        *(uint4*)&As[sar][sak] = apk;
#pragma unroll
        for (int j = 0; j < 3; j++) {
            *(uint4*)&Bs[rows[j]][kofs[j]] = bv[j][0];
            *(uint4*)&Bs[rows[j]][kofs[j] + 8] = bv[j][1];
        }
        __syncthreads();
        bf16x8 af = *(const bf16x8*)&As[16 * wv + l16][q * 8];
#pragma unroll
        for (int t = 0; t < 24; t++) {
            bf16x8 bf = *(const bf16x8*)&Bs[t * 16 + l16][q * 8];
            acc[t] = __builtin_amdgcn_mfma_f32_16x16x32_bf16(af, bf, acc[t], 0, 0, 0);
        }
    }
    const float* bs[3] = {b0, b1, b2};
#pragma unroll
    for (int s = 0; s < 3; s++) {
#pragma unroll
        for (int t8 = 0; t8 < 8; t8++) {
            int t = s * 8 + t8;
            int col = t8 * 16 + l16;
            float bb = bs[s] ? bs[s][col] : 0.f;
#pragma unroll
            for (int r = 0; r < 4; r++) {
                int row = m0 + 16 * wv + q * 4 + r;
                bool ok = row < M;
                float val = acc[t][r] + bb;
                float other = __shfl_xor(val, 1);
                if (!(lane & 1) && ok) {
                    unsigned int pk = f2bu(val) | (f2bu(other) << 16);
                    if (s == 0)
                        *(unsigned int*)(qb + (size_t)row * 128 + col) = pk;
                    else
                        *(unsigned int*)(kv + (size_t)row * 256 + (s - 1) * 128 + col) = pk;
                }
            }
        }
    }
}

// ---------- LayerNorm(128)+ReLU ----------
__global__ void ln_relu_kernel(float* __restrict__ X, int ld,
                               const float* __restrict__ g,
                               const float* __restrict__ b, int M,
                               int wfp32, ushort_t* __restrict__ Xb)
{
    int node = blockIdx.x * 4 + (threadIdx.x >> 6);
    int lane = threadIdx.x & 63;
    if (node >= M) return;
    float* row = X + (size_t)node * ld;
    float2 v = *(float2*)(row + lane * 2);
    float s = v.x + v.y, sq = v.x * v.x + v.y * v.y;
#pragma unroll
    for (int off = 32; off; off >>= 1) { s += __shfl_xor(s, off); sq += __shfl_xor(sq, off); }
    float mean = s * (1.f / 128.f);
    float var = sq * (1.f / 128.f) - mean * mean;
    float inv = rsqrtf(var + 1e-5f);
    float y0 = fmaxf((v.x - mean) * inv * g[lane * 2] + b[lane * 2], 0.f);
    float y1 = fmaxf((v.y - mean) * inv * g[lane * 2 + 1] + b[lane * 2 + 1], 0.f);
    if (wfp32) *(float2*)(row + lane * 2) = make_float2(y0, y1);
    if (Xb) {
        unsigned int p = f2bu(y0) | (f2bu(y1) << 16);
        *(unsigned int*)(Xb + (size_t)node * 128 + lane * 2) = p;
    }
}

// ---------- router (fp32 exact) ----------
__global__ void router_kernel(const float* __restrict__ hr, const float* __restrict__ rW,
                              float* __restrict__ gates, int M)
{
    int node = blockIdx.x * 4 + (threadIdx.x >> 6);
    int lane = threadIdx.x & 63;
    if (node >= M) return;
    const float* row = hr + (size_t)node * 256;
    float a0 = 0, a1 = 0, a2 = 0, a3 = 0;
#pragma unroll
    for (int i = 0; i < 4; i++) {
        int k = lane + i * 64;
        float xv = row[k];
        float4 wv = *(const float4*)(rW + k * 4);
        a0 = fmaf(xv, wv.x, a0); a1 = fmaf(xv, wv.y, a1);
        a2 = fmaf(xv, wv.z, a2); a3 = fmaf(xv, wv.w, a3);
    }
#pragma unroll
    for (int off = 32; off; off >>= 1) {
        a0 += __shfl_xor(a0, off); a1 += __shfl_xor(a1, off);
        a2 += __shfl_xor(a2, off); a3 += __shfl_xor(a3, off);
    }
    if (lane == 0) {
        float l[4] = {a0 * (1.f / 1.5f), a1 * (1.f / 1.5f), a2 * (1.f / 1.5f), a3 * (1.f / 1.5f)};
        float mx = fmaxf(fmaxf(l[0], l[1]), fmaxf(l[2], l[3]));
        float e[4], ssum = 0.f;
#pragma unroll
        for (int i = 0; i < 4; i++) { e[i] = expf(l[i] - mx); ssum += e[i]; }
        float p[4];
#pragma unroll
        for (int i = 0; i < 4; i++) p[i] = e[i] / ssum;
        int i0 = 0;
        for (int i = 1; i < 4; i++) if (p[i] > p[i0]) i0 = i;
        int i1 = -1;
        for (int i = 0; i < 4; i++) {
            if (i == i0) continue;
            if (i1 < 0 || p[i] > p[i1]) i1 = i;
        }
        float wsum = fmaxf(p[i0] + p[i1], 1e-9f);
        float gg[4] = {0.f, 0.f, 0.f, 0.f};
        gg[i0] = p[i0] / wsum;
        gg[i1] = p[i1] / wsum;
        *(float4*)(gates + (size_t)node * 4) = make_float4(gg[0], gg[1], gg[2], gg[3]);
    }
}

// ---------- graph structure ----------
__global__ void edge_deg_kernel(const int* __restrict__ dst, int* __restrict__ degi, int E) {
    int e = blockIdx.x * blockDim.x + threadIdx.x;
    if (e < E) atomicAdd(&degi[dst[e]], 1);
}
__global__ void csr_fill_kernel(const int* __restrict__ src, const int* __restrict__ dst,
                                const int* __restrict__ rowptr, int* __restrict__ cursor,
                                int* __restrict__ csr, int E) {
    int e = blockIdx.x * blockDim.x + threadIdx.x;
    if (e >= E) return;
    int d = dst[e];
    int pos = atomicAdd(&cursor[d], 1);
    csr[rowptr[d] + pos] = src[e];
}

// ---------- gather: bf16 in -> bf16 out ----------
__global__ void gather_kernel(const ushort_t* __restrict__ Xb, ushort_t* __restrict__ Outb,
                              const int* __restrict__ rowptr, const int* __restrict__ csr,
                              const float* __restrict__ dv, int self_loop, float scale,
                              const float* __restrict__ bias, int relu, int M)
{
    int node = blockIdx.x * 4 + (threadIdx.x >> 6);
    int lane = threadIdx.x & 63;
    if (node >= M) return;
    int beg = rowptr[node], end = rowptr[node + 1];
    float dn = dv[node];
    float ax = 0.f, ay = 0.f;
    int e = beg;
    for (; e + 3 < end; e += 4) {
        int s0 = csr[e], s1 = csr[e + 1], s2 = csr[e + 2], s3 = csr[e + 3];
        float c0 = dn * dv[s0], c1 = dn * dv[s1], c2 = dn * dv[s2], c3 = dn * dv[s3];
        unsigned int u0 = *(const unsigned int*)(Xb + (size_t)s0 * 128 + lane * 2);
        unsigned int u1 = *(const unsigned int*)(Xb + (size_t)s1 * 128 + lane * 2);
        unsigned int u2 = *(const unsigned int*)(Xb + (size_t)s2 * 128 + lane * 2);
        unsigned int u3 = *(const unsigned int*)(Xb + (size_t)s3 * 128 + lane * 2);
        ax = fmaf(c0, bf2f(u0 & 0xffff), fmaf(c1, bf2f(u1 & 0xffff),
             fmaf(c2, bf2f(u2 & 0xffff), fmaf(c3, bf2f(u3 & 0xffff), ax))));
        ay = fmaf(c0, bf2f(u0 >> 16), fmaf(c1, bf2f(u1 >> 16),
             fmaf(c2, bf2f(u2 >> 16), fmaf(c3, bf2f(u3 >> 16), ay))));
    }
    for (; e < end; e++) {
        int s = csr[e];
        float c = dn * dv[s];
        unsigned int u = *(const unsigned int*)(Xb + (size_t)s * 128 + lane * 2);
        ax = fmaf(c, bf2f(u & 0xffff), ax);
        ay = fmaf(c, bf2f(u >> 16), ay);
    }
    if (self_loop) {
        float c = dn * dn;
        unsigned int u = *(const unsigned int*)(Xb + (size_t)node * 128 + lane * 2);
        ax = fmaf(c, bf2f(u & 0xffff), ax);
        ay = fmaf(c, bf2f(u >> 16), ay);
    }
    ax *= scale; ay *= scale;
    if (bias) { ax += bias[lane * 2]; ay += bias[lane * 2 + 1]; }
    if (relu) { ax = fmaxf(ax, 0.f); ay = fmaxf(ay, 0.f); }
    unsigned int pk = f2bu(ax) | (f2bu(ay) << 16);
    *(unsigned int*)(Outb + (size_t)node * 128 + lane * 2) = pk;
}

// ---------- dual gather (same input, two weightings): layer-1 Cheb + GCN ----------
__global__ void gather2_kernel(const ushort_t* __restrict__ Xb,
                               ushort_t* __restrict__ OutA, ushort_t* __restrict__ OutB,
                               const int* __restrict__ rowptr, const int* __restrict__ csr,
                               const float* __restrict__ dinv, const float* __restrict__ dinvl,
                               int M)
{
    int node = blockIdx.x * 4 + (threadIdx.x >> 6);
    int lane = threadIdx.x & 63;
    if (node >= M) return;
    int beg = rowptr[node], end = rowptr[node + 1];
    float dn = dinv[node], dnl = dinvl[node];
    float axA = 0.f, ayA = 0.f, axB = 0.f, ayB = 0.f;
    int e = beg;
    for (; e + 1 < end; e += 2) {
        int s0 = csr[e], s1 = csr[e + 1];
        float c0 = dn * dinv[s0], c1 = dn * dinv[s1];
        float l0 = dnl * dinvl[s0], l1 = dnl * dinvl[s1];
        unsigned int u0 = *(const unsigned int*)(Xb + (size_t)s0 * 128 + lane * 2);
        unsigned int u1 = *(const unsigned int*)(Xb + (size_t)s1 * 128 + lane * 2);
        float x00 = bf2f(u0 & 0xffff), x01 = bf2f(u0 >> 16);
        float x10 = bf2f(u1 & 0xffff), x11 = bf2f(u1 >> 16);
        axA = fmaf(c0, x00, fmaf(c1, x10, axA));
        ayA = fmaf(c0, x01, fmaf(c1, x11, ayA));
        axB = fmaf(l0, x00, fmaf(l1, x10, axB));
        ayB = fmaf(l0, x01, fmaf(l1, x11, ayB));
    }
    for (; e < end; e++) {
        int s = csr[e];
        float c = dn * dinv[s], l = dnl * dinvl[s];
        unsigned int u = *(const unsigned int*)(Xb + (size_t)s * 128 + lane * 2);
        float x0 = bf2f(u & 0xffff), x1 = bf2f(u >> 16);
        axA = fmaf(c, x0, axA); ayA = fmaf(c, x1, ayA);
        axB = fmaf(l, x0, axB); ayB = fmaf(l, x1, ayB);
    }
    {
        float c = dnl * dnl;
        unsigned int u = *(const unsigned int*)(Xb + (size_t)node * 128 + lane * 2);
        axB = fmaf(c, bf2f(u & 0xffff), axB);
        ayB = fmaf(c, bf2f(u >> 16), ayB);
    }
    size_t ofs = (size_t)node * 128 + lane * 2;
    *(unsigned int*)(OutA + ofs) = f2bu(-axA) | (f2bu(-ayA) << 16);
    *(unsigned int*)(OutB + ofs) = f2bu(axB) | (f2bu(ayB) << 16);
}

// ---------- dual-input gather: layer-2 Cheb (XA, dinv, *-1) + GCN (XB, dinvl, self-loop) ----------
__global__ void gather_l2_kernel(const ushort_t* __restrict__ XA, const ushort_t* __restrict__ XB,
                                 ushort_t* __restrict__ OutA, ushort_t* __restrict__ OutB,
                                 const int* __restrict__ rowptr, const int* __restrict__ csr,
                                 const float* __restrict__ dinv, const float* __restrict__ dinvl,
                                 int M)
{
    int node = blockIdx.x * 4 + (threadIdx.x >> 6);
    int lane = threadIdx.x & 63;
    if (node >= M) return;
    int beg = rowptr[node], end = rowptr[node + 1];
    float dn = dinv[node], dnl = dinvl[node];
    float axA = 0.f, ayA = 0.f, axB = 0.f, ayB = 0.f;
    int e = beg;
    for (; e + 1 < end; e += 2) {
        int s0 = csr[e], s1 = csr[e + 1];
        float c0 = dn * dinv[s0], c1 = dn * dinv[s1];
        float l0 = dnl * dinvl[s0], l1 = dnl * dinvl[s1];
        unsigned int a0 = *(const unsigned int*)(XA + (size_t)s0 * 128 + lane * 2);
        unsigned int a1 = *(const unsigned int*)(XA + (size_t)s1 * 128 + lane * 2);
        unsigned int b0 = *(const unsigned int*)(XB + (size_t)s0 * 128 + lane * 2);
        unsigned int b1 = *(const unsigned int*)(XB + (size_t)s1 * 128 + lane * 2);
        axA = fmaf(c0, bf2f(a0 & 0xffff), fmaf(c1, bf2f(a1 & 0xffff), axA));
        ayA = fmaf(c0, bf2f(a0 >> 16), fmaf(c1, bf2f(a1 >> 16), ayA));
        axB = fmaf(l0, bf2f(b0 & 0xffff), fmaf(l1, bf2f(b1 & 0xffff), axB));
        ayB = fmaf(l0, bf2f(b0 >> 16), fmaf(l1, bf2f(b1 >> 16), ayB));
    }
    for (; e < end; e++) {
        int s = csr[e];
        float c = dn * dinv[s], l = dnl * dinvl[s];
        unsigned int a = *(const unsigned int*)(XA + (size_t)s * 128 + lane * 2);
        unsigned int b = *(const unsigned int*)(XB + (size_t)s * 128 + lane * 2);
        axA = fmaf(c, bf2f(a & 0xffff), axA); ayA = fmaf(c, bf2f(a >> 16), ayA);
        axB = fmaf(l, bf2f(b & 0xffff), axB); ayB = fmaf(l, bf2f(b >> 16), ayB);
    }
    {
        float c = dnl * dnl;
        unsigned int b = *(const unsigned int*)(XB + (size_t)node * 128 + lane * 2);
        axB = fmaf(c, bf2f(b & 0xffff), axB);
        ayB = fmaf(c, bf2f(b >> 16), ayB);
    }
    size_t ofs = (size_t)node * 128 + lane * 2;
    *(unsigned int*)(OutA + ofs) = f2bu(-axA) | (f2bu(-ayA) << 16);
    *(unsigned int*)(OutB + ofs) = f2bu(axB) | (f2bu(ayB) << 16);
}

// ---------- attention: 2 waves per node, LDS combine ----------
__global__ __launch_bounds__(256)
void gt_attn_kernel(const ushort_t* __restrict__ Qb, const ushort_t* __restrict__ KV,
                    const int* __restrict__ rowptr, const int* __restrict__ csr,
                    ushort_t* __restrict__ Outb, int M)
{
    const float SCL = 0.17677669529663689f * 1.4426950408889634f;
    __shared__ float sden[4][64], sax[4][64], say[4][64];
    int widx = threadIdx.x >> 6;            // 0..3
    int node = blockIdx.x * 2 + (widx >> 1);
    int wsub = widx & 1;                    // wave-in-node
    int lane = threadIdx.x & 63;
    float den = 0.f, ax = 0.f, ay = 0.f;
    int beg = 0, end = 0;
    float qx = 0.f, qy = 0.f;
    if (node < M) {
        beg = rowptr[node]; end = rowptr[node + 1];
        unsigned int qu = *(const unsigned int*)(Qb + (size_t)node * 128 + lane * 2);
        qx = bf2f(qu & 0xffff) * SCL; qy = bf2f(qu >> 16) * SCL;
        for (int e0 = beg + wsub * 4; e0 < end; e0 += 8) {
            int cnt = end - e0;
            if (cnt >= 4) {
                int s0 = csr[e0], s1 = csr[e0 + 1], s2 = csr[e0 + 2], s3 = csr[e0 + 3];
                unsigned int k0 = *(const unsigned int*)(KV + (size_t)s0 * 256 + lane * 2);
                unsigned int k1 = *(const unsigned int*)(KV + (size_t)s1 * 256 + lane * 2);
                unsigned int k2 = *(const unsigned int*)(KV + (size_t)s2 * 256 + lane * 2);
                unsigned int k3 = *(const unsigned int*)(KV + (size_t)s3 * 256 + lane * 2);
                unsigned int v0 = *(const unsigned int*)(KV + (size_t)s0 * 256 + 128 + lane * 2);
                unsigned int v1 = *(const unsigned int*)(KV + (size_t)s1 * 256 + 128 + lane * 2);
                unsigned int v2 = *(const unsigned int*)(KV + (size_t)s2 * 256 + 128 + lane * 2);
                unsigned int v3 = *(const unsigned int*)(KV + (size_t)s3 * 256 + 128 + lane * 2);
                float p0 = qx * bf2f(k0 & 0xffff) + qy * bf2f(k0 >> 16);
                float p1 = qx * bf2f(k1 & 0xffff) + qy * bf2f(k1 >> 16);
                float p2 = qx * bf2f(k2 & 0xffff) + qy * bf2f(k2 >> 16);
                float p3 = qx * bf2f(k3 & 0xffff) + qy * bf2f(k3 >> 16);
#pragma unroll
                for (int off = 1; off <= 8; off <<= 1) {
                    p0 += __shfl_xor(p0, off); p1 += __shfl_xor(p1, off);
                    p2 += __shfl_xor(p2, off); p3 += __shfl_xor(p3, off);
                }
                float w0 = exp2f(fminf(p0, 80.f));
                float w1 = exp2f(fminf(p1, 80.f));
                float w2 = exp2f(fminf(p2, 80.f));
                float w3 = exp2f(fminf(p3, 80.f));
                den += (w0 + w1) + (w2 + w3);
                ax = fmaf(w0, bf2f(v0 & 0xffff), fmaf(w1, bf2f(v1 & 0xffff),
                     fmaf(w2, bf2f(v2 & 0xffff), fmaf(w3, bf2f(v3 & 0xffff), ax))));
                ay = fmaf(w0, bf2f(v0 >> 16), fmaf(w1, bf2f(v1 >> 16),
                     fmaf(w2, bf2f(v2 >> 16), fmaf(w3, bf2f(v3 >> 16), ay))));
            } else {
                for (int e = e0; e < end; e++) {
                    int s = csr[e];
                    unsigned int ku = *(const unsigned int*)(KV + (size_t)s * 256 + lane * 2);
                    unsigned int vu = *(const unsigned int*)(KV + (size_t)s * 256 + 128 + lane * 2);
                    float p = qx * bf2f(ku & 0xffff) + qy * bf2f(ku >> 16);
#pragma unroll
                    for (int off = 1; off <= 8; off <<= 1) p += __shfl_xor(p, off);
                    float w = exp2f(fminf(p, 80.f));
                    den += w;
                    ax = fmaf(w, bf2f(vu & 0xffff), ax);
                    ay = fmaf(w, bf2f(vu >> 16), ay);
                }
            }
        }
    }
    sden[widx][lane] = den; sax[widx][lane] = ax; say[widx][lane] = ay;
    __syncthreads();
    if (wsub == 0 && node < M) {
        den += sden[widx + 1][lane];
        ax += sax[widx + 1][lane];
        ay += say[widx + 1][lane];
        float d = fmaxf(den, 1e-9f);
        unsigned int pk = f2bu(ax / d) | (f2bu(ay / d) << 16);
        *(unsigned int*)(Outb + (size_t)node * 128 + lane * 2) = pk;
    }
}

// ---------- fused combine + pool phase 1 ----------
__global__ void pool_combine_kernel(const ushort_t* __restrict__ hb,
                                    const ushort_t* __restrict__ e0, const ushort_t* __restrict__ e1,
                                    const ushort_t* __restrict__ e2, const ushort_t* __restrict__ e3,
                                    const float* __restrict__ gates,
                                    const float* __restrict__ png, const float* __restrict__ pnb,
                                    const float* __restrict__ esc,
                                    const int* __restrict__ bstart, const int* __restrict__ bend,
                                    float* __restrict__ partial)
{
    int b = blockIdx.x, c = blockIdx.y;
    int lane = threadIdx.x;   // 64
    int s0 = bstart[b], e0i = bend[b];
    const ushort_t* eps[4] = {e0, e1, e2, e3};
    float ga[4], gb[4], ba[4], bb[4], es[4];
#pragma unroll
    for (int ee = 0; ee < 4; ee++) {
        ga[ee] = png[ee * 128 + lane * 2];
        gb[ee] = png[ee * 128 + lane * 2 + 1];
        ba[ee] = pnb[ee * 128 + lane * 2];
        bb[ee] = pnb[ee * 128 + lane * 2 + 1];
        es[ee] = esc[ee];
    }
    float sx = 0.f, sy = 0.f;
    for (int n = s0 + c; n < e0i; n += PCH) {
        size_t ofs = (size_t)n * 128 + lane * 2;
        float4 gg = *(const float4*)(gates + (size_t)n * 4);
        float gv[4] = {gg.x, gg.y, gg.z, gg.w};
        unsigned int hu = *(const unsigned int*)(hb + ofs);
        float ox = bf2f(hu & 0xffff), oy = bf2f(hu >> 16);
#pragma unroll
        for (int ee = 0; ee < 4; ee++) {
            unsigned int u = *(const unsigned int*)(eps[ee] + ofs);
            float vx = bf2f(u & 0xffff), vy = bf2f(u >> 16);
            float su = vx + vy, sq = vx * vx + vy * vy;
#pragma unroll
            for (int off = 32; off; off >>= 1) { su += __shfl_xor(su, off); sq += __shfl_xor(sq, off); }
            float mean = su * (1.f / 128.f);
            float var = sq * (1.f / 128.f) - mean * mean;
            float inv = rsqrtf(var + 1e-5f);
            float cc = es[ee] * gv[ee];
            ox = fmaf(cc, (vx - mean) * inv * ga[ee] + ba[ee], ox);
            oy = fmaf(cc, (vy - mean) * inv * gb[ee] + bb[ee], oy);
        }
        sx += ox; sy += oy;
    }
    *(float2*)(partial + ((size_t)b * PCH + c) * 128 + lane * 2) = make_float2(sx, sy);
}
__global__ void pool_reduce_kernel(const float* __restrict__ partial,
                                   const int* __restrict__ bstart, const int* __restrict__ bend,
                                   float* __restrict__ pooled)
{
    int b = blockIdx.x, t = threadIdx.x;
    float sum = 0.f;
#pragma unroll
    for (int c = 0; c < PCH; c++) sum += partial[((size_t)b * PCH + c) * 128 + t];
    float cnt = fmaxf((float)(bend[b] - bstart[b]), 1.f);
    pooled[(size_t)b * 128 + t] = sum / cnt;
}

// ---------- classification head ----------
__global__ void head_kernel(const float* __restrict__ pooled,
                            const float* __restrict__ h1W, const float* __restrict__ h1b,
                            const float* __restrict__ h1g, const float* __restrict__ h1be,
                            const float* __restrict__ h2W, const float* __restrict__ h2b,
                            const float* __restrict__ h2g, const float* __restrict__ h2be,
                            const float* __restrict__ h3W, const float* __restrict__ h3b,
                            const float* __restrict__ lbias,
                            float* __restrict__ out, int B)
{
    __shared__ float p[128], z[128];
    int b = blockIdx.x, t = threadIdx.x;
    p[t] = pooled[(size_t)b * 128 + t];
    __syncthreads();
    float a = h1b[t];
    for (int k = 0; k < 128; k++) a = fmaf(p[k], h1W[k * 128 + t], a);
    z[t] = a;
    __syncthreads();
    float s = 0.f, sq = 0.f;
    for (int k = 0; k < 128; k++) { float x = z[k]; s += x; sq += x * x; }
    float mean = s * (1.f / 128.f), var = sq * (1.f / 128.f) - mean * mean;
    float y = fmaxf((a - mean) * rsqrtf(var + 1e-5f) * h1g[t] + h1be[t], 0.f);
    __syncthreads();
    z[t] = y;
    __syncthreads();
    float a2 = 0.f;
    if (t < 64) {
        a2 = h2b[t];
        for (int k = 0; k < 128; k++) a2 = fmaf(z[k], h2W[k * 64 + t], a2);
    }
    __syncthreads();
    if (t < 64) p[t] = a2;
    __syncthreads();
    if (t < 2) {
        float s2 = 0.f, sq2 = 0.f;
        for (int k = 0; k < 64; k++) { float x = p[k]; s2 += x; sq2 += x * x; }
        float mean2 = s2 * (1.f / 64.f), var2 = sq2 * (1.f / 64.f) - mean2 * mean2;
        float inv2 = rsqrtf(var2 + 1e-5f);
        float o = h3b[t] + lbias[t];
        for (int k = 0; k < 64; k++) {
            float zc = fmaxf((p[k] - mean2) * inv2 * h2g[k] + h2be[k], 0.f);
            o = fmaf(zc, h3W[k * 2 + t], o);
        }
        out[b * 2 + t] = o;
    }
}

// ---------------- launch ----------------
extern "C" void kernel_launch(void* const* d_in, const int* in_sizes, int n_in,
                              void* d_out, int out_size, void* d_ws, size_t ws_size,
                              hipStream_t stream)
{
    (void)ws_size; (void)n_in;
    const int N = in_sizes[3];
    const int E = in_sizes[2] / 2;
    const int B = out_size / 2;

    const int* ei = (const int*)d_in[2];
    const int* src = ei;
    const int* dst = ei + E;
    const int* batch = (const int*)d_in[3];

    const float* W[47];
    for (int i = 0; i < 47; i++) W[i] = (const float*)d_in[i];

    size_t fN = (size_t)N;
    float* hr     = (float*)d_ws;            // 256N
    float* htmp   = hr + 256 * fN;           // 128N
    float* gates  = htmp + 128 * fN;         // 4N
    float* dinv   = gates + 4 * fN;          // N
    float* dinvl  = dinv + fN;               // N
    float* pooled = dinvl + fN;              // 128*B
    float* partial = pooled + (size_t)128 * B;
    ushort_t* hb  = (ushort_t*)(partial + (size_t)128 * B * PCH);
    ushort_t* e0b = hb + 128 * fN;
    ushort_t* e1b = e0b + 128 * fN;
    ushort_t* e2b = e1b + 128 * fN;
    ushort_t* e3b = e2b + 128 * fN;
    ushort_t* x0  = e3b + 128 * fN;
    ushort_t* x1  = x0 + 128 * fN;
    ushort_t* x2  = x1 + 128 * fN;
    ushort_t* x3  = x2 + 128 * fN;
    ushort_t* qb  = x3 + 128 * fN;
    ushort_t* kvb = qb + 128 * fN;           // 256N
    ushort_t* wt  = kvb + 256 * fN;
    WtPack wp;
    const float* wsrc[NWT] = {
        W[4], W[8], W[12], W[17], W[19],
        W[21], W[21] + 16384, W[21] + 32768, W[21] + 49152,
        W[23], W[25], W[27],
        W[23] + 16384, W[25] + 16384, W[27] + 16384,
        W[29], W[29] + 16384,
        W[31], W[31] + 16384
    };
    const int wk[NWT] = {200, 128, 256, 128, 128,
                         128, 128, 128, 128,
                         128, 128, 128,
                         128, 128, 128,
                         128, 128,
                         128, 128};
    unsigned long long woff[NWT];
    unsigned long long acc_off = 0;
    for (int i = 0; i < NWT; i++) {
        wp.src[i] = wsrc[i];
        wp.K[i] = wk[i];
        wp.off[i] = acc_off;
        woff[i] = acc_off;
        acc_off += (unsigned long long)128 * wk[i];
    }
    int* degi   = (int*)(wt + acc_off + 8);
    int* cursor = degi + N;
    int* rowptr = cursor + N;
    int* csr    = rowptr + (N + 1);
    int* bstart = csr + E;
    int* bend   = bstart + B;
    int* bsum   = bend + B;

    dim3 blk(256);
    int gN4 = (N + 3) / 4;
    int gN2 = (N + 1) / 2;
    dim3 gG((N + 63) / 64);
    int nsb = (N + SCH - 1) / SCH;

    // weights + graph structure
    wconv_kernel<<<dim3(32, NWT), blk, 0, stream>>>(wp, wt);
    zero_i32_kernel<<<(2 * N + 255) / 256, blk, 0, stream>>>(degi, 2 * N);
    zero_i32_kernel<<<1, blk, 0, stream>>>(bstart, 2 * B);
    seg_bounds_kernel<<<(N + 255) / 256, blk, 0, stream>>>(batch, bstart, bend, N);
    edge_deg_kernel<<<(E + 255) / 256, blk, 0, stream>>>(dst, degi, E);
    scan1_kernel<<<dim3(nsb), blk, 0, stream>>>(degi, rowptr, bsum, N);
    scan2_kernel<<<1, blk, 0, stream>>>(bsum, nsb);
    scan3_kernel<<<(N + 255) / 256, blk, 0, stream>>>(rowptr, bsum, degi, dinv, dinvl, N);
    csr_fill_kernel<<<(E + 255) / 256, blk, 0, stream>>>(src, dst, rowptr, cursor, csr, E);

    // encoders + fuse + router (fp32 hr path, exact gating)
    gemm_f32_kernel<<<gG, blk, 0, stream>>>(W[0], 200, wt + woff[0], hr, 256, N, 200, W[5]);
    gemm_f32_kernel<<<gG, blk, 0, stream>>>(W[1], 128, wt + woff[1], hr + 128, 256, N, 128, W[9]);
    ln_relu_kernel<<<gN4, blk, 0, stream>>>(hr, 256, W[6], W[7], N, 1, (ushort_t*)0);
    ln_relu_kernel<<<gN4, blk, 0, stream>>>(hr + 128, 256, W[10], W[11], N, 1, (ushort_t*)0);
    router_kernel<<<gN4, blk, 0, stream>>>(hr, W[16], gates, N);
    gemm_f32_kernel<<<gG, blk, 0, stream>>>(hr, 256, wt + woff[2], htmp, 128, N, 256, W[13]);
    ln_relu_kernel<<<gN4, blk, 0, stream>>>(htmp, 128, W[14], W[15], N, 0, hb);

    // expert 0: MLP
    gemm_bf_kernel<<<gG, blk, 0, stream>>>(hb, wt + woff[3], x0, N, W[18], RELUF);
    gemm_bf_kernel<<<gG, blk, 0, stream>>>(x0, wt + woff[4], e0b, N, W[20], 0);

    // layer-1 gather (shared input h): x1 = -aprop_dinv(h), x2 = gcn-gather(h)
    gather2_kernel<<<gN4, blk, 0, stream>>>(hb, x1, x2, rowptr, csr, dinv, dinvl, N);

    // layer-1 GEMMs: Cheb z1 -> x0; GCN z1 -> x1 (x1 consumed above)
    gemm_dual_kernel<<<gG, blk, 0, stream>>>(hb, wt + woff[5], x1, wt + woff[6],
                                             x0, N, W[22], RELUF);
    gemm_bf_kernel<<<gG, blk, 0, stream>>>(x2, wt + woff[17], x1, N, W[32], RELUF);

    // fused layer-2 gather: x3 = -aprop_dinv(x0) [Cheb], x2 = gcn-gather(x1) [GCN]
    gather_l2_kernel<<<gN4, blk, 0, stream>>>(x0, x1, x3, x2, rowptr, csr, dinv, dinvl, N);

    // layer-2 GEMMs
    gemm_dual_kernel<<<gG, blk, 0, stream>>>(x0, wt + woff[7], x3, wt + woff[8],
                                             e1b, N, W[22] + 128, 0);
    gemm_bf_kernel<<<gG, blk, 0, stream>>>(x2, wt + woff[18], e3b, N, W[32] + 128, 0);

    // expert 2: Graph Transformer (2 layers)
    gemm3_kernel<<<gG, blk, 0, stream>>>(hb, wt + woff[9], qb, N, W[24], W[26], W[28], kvb);
    gt_attn_kernel<<<gN2, blk, 0, stream>>>(qb, kvb, rowptr, csr, x1, N);
    gemm_bf_kernel<<<gG, blk, 0, stream>>>(hb, wt + woff[15], x1, N, W[30], ACCF | RELUF);
    gemm3_kernel<<<gG, blk, 0, stream>>>(x1, wt + woff[12], qb, N,
                                         W[24] + 128, W[26] + 128, W[28] + 128, kvb);
    gt_attn_kernel<<<gN2, blk, 0, stream>>>(qb, kvb, rowptr, csr, e2b, N);
    gemm_bf_kernel<<<gG, blk, 0, stream>>>(x1, wt + woff[16], e2b, N, W[30] + 128, ACCF);

    // fused combine+pool + head
    pool_combine_kernel<<<dim3(B, PCH), dim3(64), 0, stream>>>(
        hb, e0b, e1b, e2b, e3b, gates, W[33], W[34], W[35], bstart, bend, partial);
    pool_reduce_kernel<<<dim3(B), dim3(128), 0, stream>>>(partial, bstart, bend, pooled);
    head_kernel<<<dim3(B), dim3(128), 0, stream>>>(pooled,
        W[36], W[37], W[38], W[39],
        W[40], W[41], W[42], W[43],
        W[44], W[45], W[46],
        (float*)d_out, B);
}

// Round 13
// 653.120 us; speedup vs baseline: 1.0206x; 1.0206x over previous
//
#include <hip/hip_runtime.h>

#define RELUF 1
#define ACCF  2
#define PCH   16
#define NWT   19
#define SCH   2048

typedef unsigned short ushort_t;
typedef __attribute__((ext_vector_type(8))) short bf16x8;
typedef __attribute__((ext_vector_type(4))) float f32x4;

__device__ __forceinline__ float bf2f(unsigned int v) {
    return __uint_as_float(v << 16);
}
__device__ __forceinline__ unsigned int f2bu(float f) {
    unsigned int u = __float_as_uint(f);
    return (u + 0x7fffu + ((u >> 16) & 1u)) >> 16;
}

// ---------------- utility ----------------
__global__ void zero_i32_kernel(int* __restrict__ p, int n) {
    int i = blockIdx.x * blockDim.x + threadIdx.x;
    if (i < n) p[i] = 0;
}
__global__ void seg_bounds_kernel(const int* __restrict__ batch, int* __restrict__ bstart,
                                  int* __restrict__ bend, int N) {
    int n = blockIdx.x * blockDim.x + threadIdx.x;
    if (n >= N) return;
    int b = batch[n];
    if (n == 0) bstart[b] = 0;
    else {
        int pb = batch[n - 1];
        if (pb != b) { bstart[b] = n; bend[pb] = n; }
    }
    if (n == N - 1) bend[b] = N;
}

// ---------- parallel 3-phase scan (+ dinv fused into phase 3) ----------
__global__ void scan1_kernel(const int* __restrict__ degi, int* __restrict__ rowptr,
                             int* __restrict__ bsum, int n) {
    __shared__ int sh[256];
    int tid = threadIdx.x;
    int base = blockIdx.x * SCH + tid * 8;
    int loc[8]; int s = 0;
#pragma unroll
    for (int j = 0; j < 8; j++) {
        int idx = base + j;
        int v = (idx < n) ? degi[idx] : 0;
        s += v; loc[j] = s;
    }
    sh[tid] = s;
    __syncthreads();
    for (int off = 1; off < 256; off <<= 1) {
        int t = (tid >= off) ? sh[tid - off] : 0;
        __syncthreads();
        sh[tid] += t;
        __syncthreads();
    }
    int prev = (tid > 0) ? sh[tid - 1] : 0;
#pragma unroll
    for (int j = 0; j < 8; j++) {
        int idx = base + j;
        if (idx < n) rowptr[idx + 1] = prev + loc[j];
    }
    if (tid == 255) bsum[blockIdx.x] = sh[255];
}
__global__ void scan2_kernel(int* __restrict__ bsum, int nb) {
    __shared__ int sh[256];
    int tid = threadIdx.x;
    sh[tid] = (tid < nb) ? bsum[tid] : 0;
    __syncthreads();
    for (int off = 1; off < 256; off <<= 1) {
        int t = (tid >= off) ? sh[tid - off] : 0;
        __syncthreads();
        sh[tid] += t;
        __syncthreads();
    }
    if (tid < nb) bsum[tid] = (tid > 0) ? sh[tid - 1] : 0;
}
__global__ void scan3_kernel(int* __restrict__ rowptr, const int* __restrict__ bsum,
                             const int* __restrict__ degi,
                             float* __restrict__ dinv, float* __restrict__ dinvl, int n) {
    int i = blockIdx.x * blockDim.x + threadIdx.x;
    if (i == 0) rowptr[0] = 0;
    if (i < n) {
        rowptr[i + 1] += bsum[i / SCH];
        float deg = (float)degi[i];
        dinv[i] = (deg > 0.f) ? rsqrtf(fmaxf(deg, 1.f)) : 0.f;
        dinvl[i] = rsqrtf(deg + 1.f);
    }
}

// ---------- batched W transpose+convert ----------
struct WtPack {
    const float* src[NWT];
    unsigned long long off[NWT];
    int K[NWT];
};
__global__ void wconv_kernel(WtPack p, ushort_t* __restrict__ base) {
    int a = blockIdx.y;
    const float* s = p.src[a];
    ushort_t* d = base + p.off[a];
    int K = p.K[a];
    int total = K * 128;
    for (int i = blockIdx.x * blockDim.x + threadIdx.x; i < total; i += gridDim.x * blockDim.x) {
        int k = i >> 7, n = i & 127;
        d[n * K + k] = (ushort_t)f2bu(s[i]);
    }
}

// ---------- fp32-A MFMA GEMM (hr path): C fp32 ----------
__global__ __launch_bounds__(256)
void gemm_f32_kernel(const float* __restrict__ A, int lda,
                     const ushort_t* __restrict__ Wt,
                     float* __restrict__ C, int ldc,
                     int M, int K,
                     const float* __restrict__ bias)
{
    __shared__ ushort_t As[64][40];
    __shared__ ushort_t Bs[128][40];
    const int tid = threadIdx.x;
    const int m0 = blockIdx.x * 64;
    const int lane = tid & 63;
    const int wv = tid >> 6;
    const int q = lane >> 4;
    const int l16 = lane & 15;
    const int sar = tid >> 2;
    const int sak = (tid & 3) << 3;
    const int sbn = tid >> 1;
    const int sbk = (tid & 1) << 4;
    const bool arow_ok = (m0 + sar) < M;
    const float* Arow = A + (size_t)(m0 + sar) * lda;
    const ushort_t* Wrow = Wt + (size_t)sbn * K;

    f32x4 acc[8];
#pragma unroll
    for (int t = 0; t < 8; t++) acc[t] = (f32x4){0.f, 0.f, 0.f, 0.f};

    for (int k0 = 0; k0 < K; k0 += 32) {
        uint4 apk;
        if (arow_ok && k0 + sak + 8 <= K) {
            float4 p0 = *(const float4*)(Arow + k0 + sak);
            float4 p1 = *(const float4*)(Arow + k0 + sak + 4);
            apk.x = f2bu(p0.x) | (f2bu(p0.y) << 16);
            apk.y = f2bu(p0.z) | (f2bu(p0.w) << 16);
            apk.z = f2bu(p1.x) | (f2bu(p1.y) << 16);
            apk.w = f2bu(p1.z) | (f2bu(p1.w) << 16);
        } else {
            unsigned int t4[4] = {0, 0, 0, 0};
            for (int j = 0; j < 8; j++) {
                int k = k0 + sak + j;
                unsigned int bv = (arow_ok && k < K) ? f2bu(Arow[k]) : 0u;
                t4[j >> 1] |= bv << ((j & 1) * 16);
            }
            apk = make_uint4(t4[0], t4[1], t4[2], t4[3]);
        }
        uint4 b0, b1;
        if (k0 + sbk + 16 <= K) {
            b0 = *(const uint4*)(Wrow + k0 + sbk);
            b1 = *(const uint4*)(Wrow + k0 + sbk + 8);
        } else {
            unsigned int t8[8] = {0, 0, 0, 0, 0, 0, 0, 0};
            for (int j = 0; j < 16; j++) {
                int k = k0 + sbk + j;
                unsigned int bv = (k < K) ? (unsigned int)Wrow[k] : 0u;
                t8[j >> 1] |= bv << ((j & 1) * 16);
            }
            b0 = make_uint4(t8[0], t8[1], t8[2], t8[3]);
            b1 = make_uint4(t8[4], t8[5], t8[6], t8[7]);
        }
        __syncthreads();
        *(uint4*)&As[sar][sak] = apk;
        *(uint4*)&Bs[sbn][sbk] = b0;
        *(uint4*)&Bs[sbn][sbk + 8] = b1;
        __syncthreads();
        bf16x8 af = *(const bf16x8*)&As[16 * wv + l16][q * 8];
#pragma unroll
        for (int t = 0; t < 8; t++) {
            bf16x8 bf = *(const bf16x8*)&Bs[t * 16 + l16][q * 8];
            acc[t] = __builtin_amdgcn_mfma_f32_16x16x32_bf16(af, bf, acc[t], 0, 0, 0);
        }
    }
#pragma unroll
    for (int t = 0; t < 8; t++) {
        int col = t * 16 + l16;
        float bb = bias ? bias[col] : 0.f;
#pragma unroll
        for (int r = 0; r < 4; r++) {
            int row = m0 + 16 * wv + q * 4 + r;
            if (row < M) C[(size_t)row * ldc + col] = acc[t][r] + bb;
        }
    }
}

// ---------- bf16-A MFMA GEMM: Cb bf16 in/out, K=128 ----------
__global__ __launch_bounds__(256)
void gemm_bf_kernel(const ushort_t* __restrict__ A,
                    const ushort_t* __restrict__ Wt,
                    ushort_t* __restrict__ Cb,
                    int M, const float* __restrict__ bias, int flags)
{
    const int K = 128;
    __shared__ ushort_t As[64][40];
    __shared__ ushort_t Bs[128][40];
    const int tid = threadIdx.x;
    const int m0 = blockIdx.x * 64;
    const int lane = tid & 63;
    const int wv = tid >> 6;
    const int q = lane >> 4;
    const int l16 = lane & 15;
    const int sar = tid >> 2;
    const int sak = (tid & 3) << 3;
    const int sbn = tid >> 1;
    const int sbk = (tid & 1) << 4;
    const bool arow_ok = (m0 + sar) < M;
    const ushort_t* Arow = A + (size_t)(m0 + sar) * K;
    const ushort_t* Wrow = Wt + (size_t)sbn * K;

    f32x4 acc[8];
#pragma unroll
    for (int t = 0; t < 8; t++) acc[t] = (f32x4){0.f, 0.f, 0.f, 0.f};

    for (int k0 = 0; k0 < K; k0 += 32) {
        uint4 apk = arow_ok ? *(const uint4*)(Arow + k0 + sak) : make_uint4(0, 0, 0, 0);
        uint4 b0 = *(const uint4*)(Wrow + k0 + sbk);
        uint4 b1 = *(const uint4*)(Wrow + k0 + sbk + 8);
        __syncthreads();
        *(uint4*)&As[sar][sak] = apk;
        *(uint4*)&Bs[sbn][sbk] = b0;
        *(uint4*)&Bs[sbn][sbk + 8] = b1;
        __syncthreads();
        bf16x8 af = *(const bf16x8*)&As[16 * wv + l16][q * 8];
#pragma unroll
        for (int t = 0; t < 8; t++) {
            bf16x8 bf = *(const bf16x8*)&Bs[t * 16 + l16][q * 8];
            acc[t] = __builtin_amdgcn_mfma_f32_16x16x32_bf16(af, bf, acc[t], 0, 0, 0);
        }
    }
#pragma unroll
    for (int t = 0; t < 8; t++) {
        int col = t * 16 + l16;
        float bb = bias ? bias[col] : 0.f;
#pragma unroll
        for (int r = 0; r < 4; r++) {
            int row = m0 + 16 * wv + q * 4 + r;
            bool ok = row < M;
            float val = acc[t][r] + bb;
            if ((flags & ACCF) && ok) val += bf2f(Cb[(size_t)row * 128 + col]);
            if (flags & RELUF) val = fmaxf(val, 0.f);
            float other = __shfl_xor(val, 1);
            if (!(lane & 1) && ok) {
                unsigned int pk = f2bu(val) | (f2bu(other) << 16);
                *(unsigned int*)(Cb + (size_t)row * 128 + col) = pk;
            }
        }
    }
}

// ---------- bf16 dual GEMM: Cb = A1@W1 + A2@W2 (+bias)(+relu) ----------
__global__ __launch_bounds__(256)
void gemm_dual_kernel(const ushort_t* __restrict__ A1, const ushort_t* __restrict__ Wt1,
                      const ushort_t* __restrict__ A2, const ushort_t* __restrict__ Wt2,
                      ushort_t* __restrict__ Cb, int M,
                      const float* __restrict__ bias, int flags)
{
    const int K = 128;
    __shared__ ushort_t As[64][40];
    __shared__ ushort_t Bs[128][40];
    const int tid = threadIdx.x;
    const int m0 = blockIdx.x * 64;
    const int lane = tid & 63;
    const int wv = tid >> 6;
    const int q = lane >> 4;
    const int l16 = lane & 15;
    const int sar = tid >> 2;
    const int sak = (tid & 3) << 3;
    const int sbn = tid >> 1;
    const int sbk = (tid & 1) << 4;
    const bool arow_ok = (m0 + sar) < M;

    f32x4 acc[8];
#pragma unroll
    for (int t = 0; t < 8; t++) acc[t] = (f32x4){0.f, 0.f, 0.f, 0.f};

    for (int ph = 0; ph < 2; ph++) {
        const ushort_t* Arow = (ph ? A2 : A1) + (size_t)(m0 + sar) * K;
        const ushort_t* Wrow = (ph ? Wt2 : Wt1) + (size_t)sbn * K;
        for (int k0 = 0; k0 < K; k0 += 32) {
            uint4 apk = arow_ok ? *(const uint4*)(Arow + k0 + sak) : make_uint4(0, 0, 0, 0);
            uint4 b0 = *(const uint4*)(Wrow + k0 + sbk);
            uint4 b1 = *(const uint4*)(Wrow + k0 + sbk + 8);
            __syncthreads();
            *(uint4*)&As[sar][sak] = apk;
            *(uint4*)&Bs[sbn][sbk] = b0;
            *(uint4*)&Bs[sbn][sbk + 8] = b1;
            __syncthreads();
            bf16x8 af = *(const bf16x8*)&As[16 * wv + l16][q * 8];
#pragma unroll
            for (int t = 0; t < 8; t++) {
                bf16x8 bf = *(const bf16x8*)&Bs[t * 16 + l16][q * 8];
                acc[t] = __builtin_amdgcn_mfma_f32_16x16x32_bf16(af, bf, acc[t], 0, 0, 0);
            }
        }
    }
#pragma unroll
    for (int t = 0; t < 8; t++) {
        int col = t * 16 + l16;
        float bb = bias ? bias[col] : 0.f;
#pragma unroll
        for (int r = 0; r < 4; r++) {
            int row = m0 + 16 * wv + q * 4 + r;
            bool ok = row < M;
            float val = acc[t][r] + bb;
            if (flags & RELUF) val = fmaxf(val, 0.f);
            float other = __shfl_xor(val, 1);
            if (!(lane & 1) && ok) {
                unsigned int pk = f2bu(val) | (f2bu(other) << 16);
                *(unsigned int*)(Cb + (size_t)row * 128 + col) = pk;
            }
        }
    }
}

// ---------- bf16 triple GEMM (QKV) ----------
__global__ __launch_bounds__(256)
void gemm3_kernel(const ushort_t* __restrict__ A,
                  const ushort_t* __restrict__ Wt,
                  ushort_t* __restrict__ qb,
                  int M,
                  const float* __restrict__ b0, const float* __restrict__ b1,
                  const float* __restrict__ b2,
                  ushort_t* __restrict__ kv)
{
    const int K = 128;
    __shared__ ushort_t As[64][40];
    __shared__ ushort_t Bs[384][40];
    const int tid = threadIdx.x;
    const int m0 = blockIdx.x * 64;
    const int lane = tid & 63;
    const int wv = tid >> 6;
    const int q = lane >> 4;
    const int l16 = lane & 15;
    const int sar = tid >> 2;
    const int sak = (tid & 3) << 3;
    const bool arow_ok = (m0 + sar) < M;
    const ushort_t* Arow = A + (size_t)(m0 + sar) * K;

    f32x4 acc[24];
#pragma unroll
    for (int t = 0; t < 24; t++) acc[t] = (f32x4){0.f, 0.f, 0.f, 0.f};

    for (int k0 = 0; k0 < K; k0 += 32) {
        uint4 apk = arow_ok ? *(const uint4*)(Arow + k0 + sak) : make_uint4(0, 0, 0, 0);
        uint4 bv[3][2];
        int rows[3], kofs[3];
#pragma unroll
        for (int j = 0; j < 3; j++) {
            int slot = tid + j * 256;
            rows[j] = slot >> 1;
            kofs[j] = (slot & 1) << 4;
            const ushort_t* Wrow = Wt + (size_t)rows[j] * K + k0 + kofs[j];
            bv[j][0] = *(const uint4*)Wrow;
            bv[j][1] = *(const uint4*)(Wrow + 8);
        }
        __syncthreads();
        *(uint4*)&As[sar][sak] = apk;
#pragma unroll
        for (int j = 0; j < 3; j++) {
            *(uint4*)&Bs[rows[j]][kofs[j]] = bv[j][0];
            *(uint4*)&Bs[rows[j]][kofs[j] + 8] = bv[j][1];
        }
        __syncthreads();
        bf16x8 af = *(const bf16x8*)&As[16 * wv + l16][q * 8];
#pragma unroll
        for (int t = 0; t < 24; t++) {
            bf16x8 bf = *(const bf16x8*)&Bs[t * 16 + l16][q * 8];
            acc[t] = __builtin_amdgcn_mfma_f32_16x16x32_bf16(af, bf, acc[t], 0, 0, 0);
        }
    }
    const float* bs[3] = {b0, b1, b2};
#pragma unroll
    for (int s = 0; s < 3; s++) {
#pragma unroll
        for (int t8 = 0; t8 < 8; t8++) {
            int t = s * 8 + t8;
            int col = t8 * 16 + l16;
            float bb = bs[s] ? bs[s][col] : 0.f;
#pragma unroll
            for (int r = 0; r < 4; r++) {
                int row = m0 + 16 * wv + q * 4 + r;
                bool ok = row < M;
                float val = acc[t][r] + bb;
                float other = __shfl_xor(val, 1);
                if (!(lane & 1) && ok) {
                    unsigned int pk = f2bu(val) | (f2bu(other) << 16);
                    if (s == 0)
                        *(unsigned int*)(qb + (size_t)row * 128 + col) = pk;
                    else
                        *(unsigned int*)(kv + (size_t)row * 256 + (s - 1) * 128 + col) = pk;
                }
            }
        }
    }
}

// ---------- LayerNorm(128)+ReLU ----------
__global__ void ln_relu_kernel(float* __restrict__ X, int ld,
                               const float* __restrict__ g,
                               const float* __restrict__ b, int M,
                               int wfp32, ushort_t* __restrict__ Xb)
{
    int node = blockIdx.x * 4 + (threadIdx.x >> 6);
    int lane = threadIdx.x & 63;
    if (node >= M) return;
    float* row = X + (size_t)node * ld;
    float2 v = *(float2*)(row + lane * 2);
    float s = v.x + v.y, sq = v.x * v.x + v.y * v.y;
#pragma unroll
    for (int off = 32; off; off >>= 1) { s += __shfl_xor(s, off); sq += __shfl_xor(sq, off); }
    float mean = s * (1.f / 128.f);
    float var = sq * (1.f / 128.f) - mean * mean;
    float inv = rsqrtf(var + 1e-5f);
    float y0 = fmaxf((v.x - mean) * inv * g[lane * 2] + b[lane * 2], 0.f);
    float y1 = fmaxf((v.y - mean) * inv * g[lane * 2 + 1] + b[lane * 2 + 1], 0.f);
    if (wfp32) *(float2*)(row + lane * 2) = make_float2(y0, y1);
    if (Xb) {
        unsigned int p = f2bu(y0) | (f2bu(y1) << 16);
        *(unsigned int*)(Xb + (size_t)node * 128 + lane * 2) = p;
    }
}

// ---------- router (fp32 exact) ----------
__global__ void router_kernel(const float* __restrict__ hr, const float* __restrict__ rW,
                              float* __restrict__ gates, int M)
{
    int node = blockIdx.x * 4 + (threadIdx.x >> 6);
    int lane = threadIdx.x & 63;
    if (node >= M) return;
    const float* row = hr + (size_t)node * 256;
    float a0 = 0, a1 = 0, a2 = 0, a3 = 0;
#pragma unroll
    for (int i = 0; i < 4; i++) {
        int k = lane + i * 64;
        float xv = row[k];
        float4 wv = *(const float4*)(rW + k * 4);
        a0 = fmaf(xv, wv.x, a0); a1 = fmaf(xv, wv.y, a1);
        a2 = fmaf(xv, wv.z, a2); a3 = fmaf(xv, wv.w, a3);
    }
#pragma unroll
    for (int off = 32; off; off >>= 1) {
        a0 += __shfl_xor(a0, off); a1 += __shfl_xor(a1, off);
        a2 += __shfl_xor(a2, off); a3 += __shfl_xor(a3, off);
    }
    if (lane == 0) {
        float l[4] = {a0 * (1.f / 1.5f), a1 * (1.f / 1.5f), a2 * (1.f / 1.5f), a3 * (1.f / 1.5f)};
        float mx = fmaxf(fmaxf(l[0], l[1]), fmaxf(l[2], l[3]));
        float e[4], ssum = 0.f;
#pragma unroll
        for (int i = 0; i < 4; i++) { e[i] = expf(l[i] - mx); ssum += e[i]; }
        float p[4];
#pragma unroll
        for (int i = 0; i < 4; i++) p[i] = e[i] / ssum;
        int i0 = 0;
        for (int i = 1; i < 4; i++) if (p[i] > p[i0]) i0 = i;
        int i1 = -1;
        for (int i = 0; i < 4; i++) {
            if (i == i0) continue;
            if (i1 < 0 || p[i] > p[i1]) i1 = i;
        }
        float wsum = fmaxf(p[i0] + p[i1], 1e-9f);
        float gg[4] = {0.f, 0.f, 0.f, 0.f};
        gg[i0] = p[i0] / wsum;
        gg[i1] = p[i1] / wsum;
        *(float4*)(gates + (size_t)node * 4) = make_float4(gg[0], gg[1], gg[2], gg[3]);
    }
}

// ---------- graph structure ----------
__global__ void edge_deg_kernel(const int* __restrict__ dst, int* __restrict__ degi, int E) {
    int e = blockIdx.x * blockDim.x + threadIdx.x;
    if (e < E) atomicAdd(&degi[dst[e]], 1);
}
__global__ void csr_fill_kernel(const int* __restrict__ src, const int* __restrict__ dst,
                                const int* __restrict__ rowptr, int* __restrict__ cursor,
                                int* __restrict__ csr, int E) {
    int e = blockIdx.x * blockDim.x + threadIdx.x;
    if (e >= E) return;
    int d = dst[e];
    int pos = atomicAdd(&cursor[d], 1);
    csr[rowptr[d] + pos] = src[e];
}

// ---------- gather: bf16 in -> bf16 out ----------
__global__ void gather_kernel(const ushort_t* __restrict__ Xb, ushort_t* __restrict__ Outb,
                              const int* __restrict__ rowptr, const int* __restrict__ csr,
                              const float* __restrict__ dv, int self_loop, float scale,
                              const float* __restrict__ bias, int relu, int M)
{
    int node = blockIdx.x * 4 + (threadIdx.x >> 6);
    int lane = threadIdx.x & 63;
    if (node >= M) return;
    int beg = rowptr[node], end = rowptr[node + 1];
    float dn = dv[node];
    float ax = 0.f, ay = 0.f;
    int e = beg;
    for (; e + 3 < end; e += 4) {
        int s0 = csr[e], s1 = csr[e + 1], s2 = csr[e + 2], s3 = csr[e + 3];
        float c0 = dn * dv[s0], c1 = dn * dv[s1], c2 = dn * dv[s2], c3 = dn * dv[s3];
        unsigned int u0 = *(const unsigned int*)(Xb + (size_t)s0 * 128 + lane * 2);
        unsigned int u1 = *(const unsigned int*)(Xb + (size_t)s1 * 128 + lane * 2);
        unsigned int u2 = *(const unsigned int*)(Xb + (size_t)s2 * 128 + lane * 2);
        unsigned int u3 = *(const unsigned int*)(Xb + (size_t)s3 * 128 + lane * 2);
        ax = fmaf(c0, bf2f(u0 & 0xffff), fmaf(c1, bf2f(u1 & 0xffff),
             fmaf(c2, bf2f(u2 & 0xffff), fmaf(c3, bf2f(u3 & 0xffff), ax))));
        ay = fmaf(c0, bf2f(u0 >> 16), fmaf(c1, bf2f(u1 >> 16),
             fmaf(c2, bf2f(u2 >> 16), fmaf(c3, bf2f(u3 >> 16), ay))));
    }
    for (; e < end; e++) {
        int s = csr[e];
        float c = dn * dv[s];
        unsigned int u = *(const unsigned int*)(Xb + (size_t)s * 128 + lane * 2);
        ax = fmaf(c, bf2f(u & 0xffff), ax);
        ay = fmaf(c, bf2f(u >> 16), ay);
    }
    if (self_loop) {
        float c = dn * dn;
        unsigned int u = *(const unsigned int*)(Xb + (size_t)node * 128 + lane * 2);
        ax = fmaf(c, bf2f(u & 0xffff), ax);
        ay = fmaf(c, bf2f(u >> 16), ay);
    }
    ax *= scale; ay *= scale;
    if (bias) { ax += bias[lane * 2]; ay += bias[lane * 2 + 1]; }
    if (relu) { ax = fmaxf(ax, 0.f); ay = fmaxf(ay, 0.f); }
    unsigned int pk = f2bu(ax) | (f2bu(ay) << 16);
    *(unsigned int*)(Outb + (size_t)node * 128 + lane * 2) = pk;
}

// ---------- dual gather (same input, two weightings): layer-1 Cheb + GCN ----------
__global__ void gather2_kernel(const ushort_t* __restrict__ Xb,
                               ushort_t* __restrict__ OutA, ushort_t* __restrict__ OutB,
                               const int* __restrict__ rowptr, const int* __restrict__ csr,
                               const float* __restrict__ dinv, const float* __restrict__ dinvl,
                               int M)
{
    int node = blockIdx.x * 4 + (threadIdx.x >> 6);
    int lane = threadIdx.x & 63;
    if (node >= M) return;
    int beg = rowptr[node], end = rowptr[node + 1];
    float dn = dinv[node], dnl = dinvl[node];
    float axA = 0.f, ayA = 0.f, axB = 0.f, ayB = 0.f;
    int e = beg;
    for (; e + 1 < end; e += 2) {
        int s0 = csr[e], s1 = csr[e + 1];
        float c0 = dn * dinv[s0], c1 = dn * dinv[s1];
        float l0 = dnl * dinvl[s0], l1 = dnl * dinvl[s1];
        unsigned int u0 = *(const unsigned int*)(Xb + (size_t)s0 * 128 + lane * 2);
        unsigned int u1 = *(const unsigned int*)(Xb + (size_t)s1 * 128 + lane * 2);
        float x00 = bf2f(u0 & 0xffff), x01 = bf2f(u0 >> 16);
        float x10 = bf2f(u1 & 0xffff), x11 = bf2f(u1 >> 16);
        axA = fmaf(c0, x00, fmaf(c1, x10, axA));
        ayA = fmaf(c0, x01, fmaf(c1, x11, ayA));
        axB = fmaf(l0, x00, fmaf(l1, x10, axB));
        ayB = fmaf(l0, x01, fmaf(l1, x11, ayB));
    }
    for (; e < end; e++) {
        int s = csr[e];
        float c = dn * dinv[s], l = dnl * dinvl[s];
        unsigned int u = *(const unsigned int*)(Xb + (size_t)s * 128 + lane * 2);
        float x0 = bf2f(u & 0xffff), x1 = bf2f(u >> 16);
        axA = fmaf(c, x0, axA); ayA = fmaf(c, x1, ayA);
        axB = fmaf(l, x0, axB); ayB = fmaf(l, x1, ayB);
    }
    {
        float c = dnl * dnl;
        unsigned int u = *(const unsigned int*)(Xb + (size_t)node * 128 + lane * 2);
        axB = fmaf(c, bf2f(u & 0xffff), axB);
        ayB = fmaf(c, bf2f(u >> 16), ayB);
    }
    size_t ofs = (size_t)node * 128 + lane * 2;
    *(unsigned int*)(OutA + ofs) = f2bu(-axA) | (f2bu(-ayA) << 16);
    *(unsigned int*)(OutB + ofs) = f2bu(axB) | (f2bu(ayB) << 16);
}

// ---------- dual-input gather: layer-2 Cheb (XA, dinv, *-1) + GCN (XB, dinvl, self-loop) ----------
__global__ void gather_l2_kernel(const ushort_t* __restrict__ XA, const ushort_t* __restrict__ XB,
                                 ushort_t* __restrict__ OutA, ushort_t* __restrict__ OutB,
                                 const int* __restrict__ rowptr, const int* __restrict__ csr,
                                 const float* __restrict__ dinv, const float* __restrict__ dinvl,
                                 int M)
{
    int node = blockIdx.x * 4 + (threadIdx.x >> 6);
    int lane = threadIdx.x & 63;
    if (node >= M) return;
    int beg = rowptr[node], end = rowptr[node + 1];
    float dn = dinv[node], dnl = dinvl[node];
    float axA = 0.f, ayA = 0.f, axB = 0.f, ayB = 0.f;
    int e = beg;
    for (; e + 1 < end; e += 2) {
        int s0 = csr[e], s1 = csr[e + 1];
        float c0 = dn * dinv[s0], c1 = dn * dinv[s1];
        float l0 = dnl * dinvl[s0], l1 = dnl * dinvl[s1];
        unsigned int a0 = *(const unsigned int*)(XA + (size_t)s0 * 128 + lane * 2);
        unsigned int a1 = *(const unsigned int*)(XA + (size_t)s1 * 128 + lane * 2);
        unsigned int b0 = *(const unsigned int*)(XB + (size_t)s0 * 128 + lane * 2);
        unsigned int b1 = *(const unsigned int*)(XB + (size_t)s1 * 128 + lane * 2);
        axA = fmaf(c0, bf2f(a0 & 0xffff), fmaf(c1, bf2f(a1 & 0xffff), axA));
        ayA = fmaf(c0, bf2f(a0 >> 16), fmaf(c1, bf2f(a1 >> 16), ayA));
        axB = fmaf(l0, bf2f(b0 & 0xffff), fmaf(l1, bf2f(b1 & 0xffff), axB));
        ayB = fmaf(l0, bf2f(b0 >> 16), fmaf(l1, bf2f(b1 >> 16), ayB));
    }
    for (; e < end; e++) {
        int s = csr[e];
        float c = dn * dinv[s], l = dnl * dinvl[s];
        unsigned int a = *(const unsigned int*)(XA + (size_t)s * 128 + lane * 2);
        unsigned int b = *(const unsigned int*)(XB + (size_t)s * 128 + lane * 2);
        axA = fmaf(c, bf2f(a & 0xffff), axA); ayA = fmaf(c, bf2f(a >> 16), ayA);
        axB = fmaf(l, bf2f(b & 0xffff), axB); ayB = fmaf(l, bf2f(b >> 16), ayB);
    }
    {
        float c = dnl * dnl;
        unsigned int b = *(const unsigned int*)(XB + (size_t)node * 128 + lane * 2);
        axB = fmaf(c, bf2f(b & 0xffff), axB);
        ayB = fmaf(c, bf2f(b >> 16), ayB);
    }
    size_t ofs = (size_t)node * 128 + lane * 2;
    *(unsigned int*)(OutA + ofs) = f2bu(-axA) | (f2bu(-ayA) << 16);
    *(unsigned int*)(OutB + ofs) = f2bu(axB) | (f2bu(ayB) << 16);
}

// ---------- attention: 1 wave/node, unroll 4, index prefetch ----------
__global__ void gt_attn_kernel(const ushort_t* __restrict__ Qb, const ushort_t* __restrict__ KV,
                               const int* __restrict__ rowptr, const int* __restrict__ csr,
                               ushort_t* __restrict__ Outb, int M)
{
    const float SCL = 0.17677669529663689f * 1.4426950408889634f;
    int node = blockIdx.x * 4 + (threadIdx.x >> 6);
    int lane = threadIdx.x & 63;
    if (node >= M) return;
    int beg = rowptr[node], end = rowptr[node + 1];
    unsigned int qu = *(const unsigned int*)(Qb + (size_t)node * 128 + lane * 2);
    float qx = bf2f(qu & 0xffff) * SCL, qy = bf2f(qu >> 16) * SCL;
    float den = 0.f, ax = 0.f, ay = 0.f;
    int e = beg;
    int ns0 = 0, ns1 = 0, ns2 = 0, ns3 = 0;
    if (e + 3 < end) { ns0 = csr[e]; ns1 = csr[e + 1]; ns2 = csr[e + 2]; ns3 = csr[e + 3]; }
    for (; e + 3 < end; e += 4) {
        int s0 = ns0, s1 = ns1, s2 = ns2, s3 = ns3;
        if (e + 7 < end) { ns0 = csr[e + 4]; ns1 = csr[e + 5]; ns2 = csr[e + 6]; ns3 = csr[e + 7]; }
        unsigned int k0 = *(const unsigned int*)(KV + (size_t)s0 * 256 + lane * 2);
        unsigned int k1 = *(const unsigned int*)(KV + (size_t)s1 * 256 + lane * 2);
        unsigned int k2 = *(const unsigned int*)(KV + (size_t)s2 * 256 + lane * 2);
        unsigned int k3 = *(const unsigned int*)(KV + (size_t)s3 * 256 + lane * 2);
        unsigned int v0 = *(const unsigned int*)(KV + (size_t)s0 * 256 + 128 + lane * 2);
        unsigned int v1 = *(const unsigned int*)(KV + (size_t)s1 * 256 + 128 + lane * 2);
        unsigned int v2 = *(const unsigned int*)(KV + (size_t)s2 * 256 + 128 + lane * 2);
        unsigned int v3 = *(const unsigned int*)(KV + (size_t)s3 * 256 + 128 + lane * 2);
        float p0 = qx * bf2f(k0 & 0xffff) + qy * bf2f(k0 >> 16);
        float p1 = qx * bf2f(k1 & 0xffff) + qy * bf2f(k1 >> 16);
        float p2 = qx * bf2f(k2 & 0xffff) + qy * bf2f(k2 >> 16);
        float p3 = qx * bf2f(k3 & 0xffff) + qy * bf2f(k3 >> 16);
#pragma unroll
        for (int off = 1; off <= 8; off <<= 1) {
            p0 += __shfl_xor(p0, off); p1 += __shfl_xor(p1, off);
            p2 += __shfl_xor(p2, off); p3 += __shfl_xor(p3, off);
        }
        float w0 = exp2f(fminf(p0, 80.f));
        float w1 = exp2f(fminf(p1, 80.f));
        float w2 = exp2f(fminf(p2, 80.f));
        float w3 = exp2f(fminf(p3, 80.f));
        den += (w0 + w1) + (w2 + w3);
        ax = fmaf(w0, bf2f(v0 & 0xffff), fmaf(w1, bf2f(v1 & 0xffff),
             fmaf(w2, bf2f(v2 & 0xffff), fmaf(w3, bf2f(v3 & 0xffff), ax))));
        ay = fmaf(w0, bf2f(v0 >> 16), fmaf(w1, bf2f(v1 >> 16),
             fmaf(w2, bf2f(v2 >> 16), fmaf(w3, bf2f(v3 >> 16), ay))));
    }
    for (; e < end; e++) {
        int s = csr[e];
        unsigned int ku = *(const unsigned int*)(KV + (size_t)s * 256 + lane * 2);
        unsigned int vu = *(const unsigned int*)(KV + (size_t)s * 256 + 128 + lane * 2);
        float p = qx * bf2f(ku & 0xffff) + qy * bf2f(ku >> 16);
#pragma unroll
        for (int off = 1; off <= 8; off <<= 1) p += __shfl_xor(p, off);
        float w = exp2f(fminf(p, 80.f));
        den += w;
        ax = fmaf(w, bf2f(vu & 0xffff), ax);
        ay = fmaf(w, bf2f(vu >> 16), ay);
    }
    float d = fmaxf(den, 1e-9f);
    unsigned int pk = f2bu(ax / d) | (f2bu(ay / d) << 16);
    *(unsigned int*)(Outb + (size_t)node * 128 + lane * 2) = pk;
}

// ---------- fused combine + pool phase 1 ----------
__global__ void pool_combine_kernel(const ushort_t* __restrict__ hb,
                                    const ushort_t* __restrict__ e0, const ushort_t* __restrict__ e1,
                                    const ushort_t* __restrict__ e2, const ushort_t* __restrict__ e3,
                                    const float* __restrict__ gates,
                                    const float* __restrict__ png, const float* __restrict__ pnb,
                                    const float* __restrict__ esc,
                                    const int* __restrict__ bstart, const int* __restrict__ bend,
                                    float* __restrict__ partial)
{
    int b = blockIdx.x, c = blockIdx.y;
    int lane = threadIdx.x;   // 64
    int s0 = bstart[b], e0i = bend[b];
    const ushort_t* eps[4] = {e0, e1, e2, e3};
    float ga[4], gb[4], ba[4], bb[4], es[4];
#pragma unroll
    for (int ee = 0; ee < 4; ee++) {
        ga[ee] = png[ee * 128 + lane * 2];
        gb[ee] = png[ee * 128 + lane * 2 + 1];
        ba[ee] = pnb[ee * 128 + lane * 2];
        bb[ee] = pnb[ee * 128 + lane * 2 + 1];
        es[ee] = esc[ee];
    }
    float sx = 0.f, sy = 0.f;
    for (int n = s0 + c; n < e0i; n += PCH) {
        size_t ofs = (size_t)n * 128 + lane * 2;
        float4 gg = *(const float4*)(gates + (size_t)n * 4);
        float gv[4] = {gg.x, gg.y, gg.z, gg.w};
        unsigned int hu = *(const unsigned int*)(hb + ofs);
        float ox = bf2f(hu & 0xffff), oy = bf2f(hu >> 16);
#pragma unroll
        for (int ee = 0; ee < 4; ee++) {
            unsigned int u = *(const unsigned int*)(eps[ee] + ofs);
            float vx = bf2f(u & 0xffff), vy = bf2f(u >> 16);
            float su = vx + vy, sq = vx * vx + vy * vy;
#pragma unroll
            for (int off = 32; off; off >>= 1) { su += __shfl_xor(su, off); sq += __shfl_xor(sq, off); }
            float mean = su * (1.f / 128.f);
            float var = sq * (1.f / 128.f) - mean * mean;
            float inv = rsqrtf(var + 1e-5f);
            float cc = es[ee] * gv[ee];
            ox = fmaf(cc, (vx - mean) * inv * ga[ee] + ba[ee], ox);
            oy = fmaf(cc, (vy - mean) * inv * gb[ee] + bb[ee], oy);
        }
        sx += ox; sy += oy;
    }
    *(float2*)(partial + ((size_t)b * PCH + c) * 128 + lane * 2) = make_float2(sx, sy);
}
__global__ void pool_reduce_kernel(const float* __restrict__ partial,
                                   const int* __restrict__ bstart, const int* __restrict__ bend,
                                   float* __restrict__ pooled)
{
    int b = blockIdx.x, t = threadIdx.x;
    float sum = 0.f;
#pragma unroll
    for (int c = 0; c < PCH; c++) sum += partial[((size_t)b * PCH + c) * 128 + t];
    float cnt = fmaxf((float)(bend[b] - bstart[b]), 1.f);
    pooled[(size_t)b * 128 + t] = sum / cnt;
}

// ---------- classification head ----------
__global__ void head_kernel(const float* __restrict__ pooled,
                            const float* __restrict__ h1W, const float* __restrict__ h1b,
                            const float* __restrict__ h1g, const float* __restrict__ h1be,
                            const float* __restrict__ h2W, const float* __restrict__ h2b,
                            const float* __restrict__ h2g, const float* __restrict__ h2be,
                            const float* __restrict__ h3W, const float* __restrict__ h3b,
                            const float* __restrict__ lbias,
                            float* __restrict__ out, int B)
{
    __shared__ float p[128], z[128];
    int b = blockIdx.x, t = threadIdx.x;
    p[t] = pooled[(size_t)b * 128 + t];
    __syncthreads();
    float a = h1b[t];
    for (int k = 0; k < 128; k++) a = fmaf(p[k], h1W[k * 128 + t], a);
    z[t] = a;
    __syncthreads();
    float s = 0.f, sq = 0.f;
    for (int k = 0; k < 128; k++) { float x = z[k]; s += x; sq += x * x; }
    float mean = s * (1.f / 128.f), var = sq * (1.f / 128.f) - mean * mean;
    float y = fmaxf((a - mean) * rsqrtf(var + 1e-5f) * h1g[t] + h1be[t], 0.f);
    __syncthreads();
    z[t] = y;
    __syncthreads();
    float a2 = 0.f;
    if (t < 64) {
        a2 = h2b[t];
        for (int k = 0; k < 128; k++) a2 = fmaf(z[k], h2W[k * 64 + t], a2);
    }
    __syncthreads();
    if (t < 64) p[t] = a2;
    __syncthreads();
    if (t < 2) {
        float s2 = 0.f, sq2 = 0.f;
        for (int k = 0; k < 64; k++) { float x = p[k]; s2 += x; sq2 += x * x; }
        float mean2 = s2 * (1.f / 64.f), var2 = sq2 * (1.f / 64.f) - mean2 * mean2;
        float inv2 = rsqrtf(var2 + 1e-5f);
        float o = h3b[t] + lbias[t];
        for (int k = 0; k < 64; k++) {
            float zc = fmaxf((p[k] - mean2) * inv2 * h2g[k] + h2be[k], 0.f);
            o = fmaf(zc, h3W[k * 2 + t], o);
        }
        out[b * 2 + t] = o;
    }
}

// ---------------- launch ----------------
extern "C" void kernel_launch(void* const* d_in, const int* in_sizes, int n_in,
                              void* d_out, int out_size, void* d_ws, size_t ws_size,
                              hipStream_t stream)
{
    (void)ws_size; (void)n_in;
    const int N = in_sizes[3];
    const int E = in_sizes[2] / 2;
    const int B = out_size / 2;

    const int* ei = (const int*)d_in[2];
    const int* src = ei;
    const int* dst = ei + E;
    const int* batch = (const int*)d_in[3];

    const float* W[47];
    for (int i = 0; i < 47; i++) W[i] = (const float*)d_in[i];

    size_t fN = (size_t)N;
    float* hr     = (float*)d_ws;            // 256N
    float* htmp   = hr + 256 * fN;           // 128N
    float* gates  = htmp + 128 * fN;         // 4N
    float* dinv   = gates + 4 * fN;          // N
    float* dinvl  = dinv + fN;               // N
    float* pooled = dinvl + fN;              // 128*B
    float* partial = pooled + (size_t)128 * B;
    ushort_t* hb  = (ushort_t*)(partial + (size_t)128 * B * PCH);
    ushort_t* e0b = hb + 128 * fN;
    ushort_t* e1b = e0b + 128 * fN;
    ushort_t* e2b = e1b + 128 * fN;
    ushort_t* e3b = e2b + 128 * fN;
    ushort_t* x0  = e3b + 128 * fN;
    ushort_t* x1  = x0 + 128 * fN;
    ushort_t* x2  = x1 + 128 * fN;
    ushort_t* x3  = x2 + 128 * fN;
    ushort_t* qb  = x3 + 128 * fN;
    ushort_t* kvb = qb + 128 * fN;           // 256N
    ushort_t* wt  = kvb + 256 * fN;
    WtPack wp;
    const float* wsrc[NWT] = {
        W[4], W[8], W[12], W[17], W[19],
        W[21], W[21] + 16384, W[21] + 32768, W[21] + 49152,
        W[23], W[25], W[27],
        W[23] + 16384, W[25] + 16384, W[27] + 16384,
        W[29], W[29] + 16384,
        W[31], W[31] + 16384
    };
    const int wk[NWT] = {200, 128, 256, 128, 128,
                         128, 128, 128, 128,
                         128, 128, 128,
                         128, 128, 128,
                         128, 128,
                         128, 128};
    unsigned long long woff[NWT];
    unsigned long long acc_off = 0;
    for (int i = 0; i < NWT; i++) {
        wp.src[i] = wsrc[i];
        wp.K[i] = wk[i];
        wp.off[i] = acc_off;
        woff[i] = acc_off;
        acc_off += (unsigned long long)128 * wk[i];
    }
    int* degi   = (int*)(wt + acc_off + 8);
    int* cursor = degi + N;
    int* rowptr = cursor + N;
    int* csr    = rowptr + (N + 1);
    int* bstart = csr + E;
    int* bend   = bstart + B;
    int* bsum   = bend + B;

    dim3 blk(256);
    int gN4 = (N + 3) / 4;
    dim3 gG((N + 63) / 64);
    int nsb = (N + SCH - 1) / SCH;

    // weights + graph structure
    wconv_kernel<<<dim3(32, NWT), blk, 0, stream>>>(wp, wt);
    zero_i32_kernel<<<(2 * N + 255) / 256, blk, 0, stream>>>(degi, 2 * N);
    zero_i32_kernel<<<1, blk, 0, stream>>>(bstart, 2 * B);
    seg_bounds_kernel<<<(N + 255) / 256, blk, 0, stream>>>(batch, bstart, bend, N);
    edge_deg_kernel<<<(E + 255) / 256, blk, 0, stream>>>(dst, degi, E);
    scan1_kernel<<<dim3(nsb), blk, 0, stream>>>(degi, rowptr, bsum, N);
    scan2_kernel<<<1, blk, 0, stream>>>(bsum, nsb);
    scan3_kernel<<<(N + 255) / 256, blk, 0, stream>>>(rowptr, bsum, degi, dinv, dinvl, N);
    csr_fill_kernel<<<(E + 255) / 256, blk, 0, stream>>>(src, dst, rowptr, cursor, csr, E);

    // encoders + fuse + router (fp32 hr path, exact gating)
    gemm_f32_kernel<<<gG, blk, 0, stream>>>(W[0], 200, wt + woff[0], hr, 256, N, 200, W[5]);
    gemm_f32_kernel<<<gG, blk, 0, stream>>>(W[1], 128, wt + woff[1], hr + 128, 256, N, 128, W[9]);
    ln_relu_kernel<<<gN4, blk, 0, stream>>>(hr, 256, W[6], W[7], N, 1, (ushort_t*)0);
    ln_relu_kernel<<<gN4, blk, 0, stream>>>(hr + 128, 256, W[10], W[11], N, 1, (ushort_t*)0);
    router_kernel<<<gN4, blk, 0, stream>>>(hr, W[16], gates, N);
    gemm_f32_kernel<<<gG, blk, 0, stream>>>(hr, 256, wt + woff[2], htmp, 128, N, 256, W[13]);
    ln_relu_kernel<<<gN4, blk, 0, stream>>>(htmp, 128, W[14], W[15], N, 0, hb);

    // expert 0: MLP
    gemm_bf_kernel<<<gG, blk, 0, stream>>>(hb, wt + woff[3], x0, N, W[18], RELUF);
    gemm_bf_kernel<<<gG, blk, 0, stream>>>(x0, wt + woff[4], e0b, N, W[20], 0);

    // layer-1 gather (shared input h): x1 = -aprop_dinv(h), x2 = gcn-gather(h)
    gather2_kernel<<<gN4, blk, 0, stream>>>(hb, x1, x2, rowptr, csr, dinv, dinvl, N);

    // layer-1 GEMMs: Cheb z1 -> x0; GCN z1 -> x1
    gemm_dual_kernel<<<gG, blk, 0, stream>>>(hb, wt + woff[5], x1, wt + woff[6],
                                             x0, N, W[22], RELUF);
    gemm_bf_kernel<<<gG, blk, 0, stream>>>(x2, wt + woff[17], x1, N, W[32], RELUF);

    // fused layer-2 gather: x3 = -aprop_dinv(x0) [Cheb], x2 = gcn-gather(x1) [GCN]
    gather_l2_kernel<<<gN4, blk, 0, stream>>>(x0, x1, x3, x2, rowptr, csr, dinv, dinvl, N);

    // layer-2 GEMMs
    gemm_dual_kernel<<<gG, blk, 0, stream>>>(x0, wt + woff[7], x3, wt + woff[8],
                                             e1b, N, W[22] + 128, 0);
    gemm_bf_kernel<<<gG, blk, 0, stream>>>(x2, wt + woff[18], e3b, N, W[32] + 128, 0);

    // expert 2: Graph Transformer (2 layers)
    gemm3_kernel<<<gG, blk, 0, stream>>>(hb, wt + woff[9], qb, N, W[24], W[26], W[28], kvb);
    gt_attn_kernel<<<gN4, blk, 0, stream>>>(qb, kvb, rowptr, csr, x1, N);
    gemm_bf_kernel<<<gG, blk, 0, stream>>>(hb, wt + woff[15], x1, N, W[30], ACCF | RELUF);
    gemm3_kernel<<<gG, blk, 0, stream>>>(x1, wt + woff[12], qb, N,
                                         W[24] + 128, W[26] + 128, W[28] + 128, kvb);
    gt_attn_kernel<<<gN4, blk, 0, stream>>>(qb, kvb, rowptr, csr, e2b, N);
    gemm_bf_kernel<<<gG, blk, 0, stream>>>(x1, wt + woff[16], e2b, N, W[30] + 128, ACCF);

    // fused combine+pool + head
    pool_combine_kernel<<<dim3(B, PCH), dim3(64), 0, stream>>>(
        hb, e0b, e1b, e2b, e3b, gates, W[33], W[34], W[35], bstart, bend, partial);
    pool_reduce_kernel<<<dim3(B), dim3(128), 0, stream>>>(partial, bstart, bend, pooled);
    head_kernel<<<dim3(B), dim3(128), 0, stream>>>(pooled,
        W[36], W[37], W[38], W[39],
        W[40], W[41], W[42], W[43],
        W[44], W[45], W[46],
        (float*)d_out, B);
}